// Round 3
// baseline (406.498 us; speedup 1.0000x reference)
//
#include <hip/hip_runtime.h>
#include <hip/hip_bf16.h>

#define N_HEAD 8
#define D_MODEL 512
#define D_HEAD 64
#define D_HIDDEN 2048
#define NTOK 64
#define BATCH 4096

typedef __attribute__((ext_vector_type(4))) float f32x4;
typedef __attribute__((ext_vector_type(8))) short short8;
typedef __attribute__((ext_vector_type(8))) unsigned short u16x8;

__device__ __forceinline__ float bf2f(unsigned short u) {
    return __uint_as_float(((unsigned int)u) << 16);
}
__device__ __forceinline__ unsigned short f2bf(float f) {
    unsigned int b = __float_as_uint(f);
    b += 0x7fffu + ((b >> 16) & 1u);
    return (unsigned short)(b >> 16);
}
__device__ __forceinline__ float wave_sum(float v) {
    v += __shfl_xor(v, 32); v += __shfl_xor(v, 16); v += __shfl_xor(v, 8);
    v += __shfl_xor(v, 4);  v += __shfl_xor(v, 2);  v += __shfl_xor(v, 1);
    return v;
}
__device__ __forceinline__ void gload_lds16(const void* g, void* l) {
    __builtin_amdgcn_global_load_lds(
        (const __attribute__((address_space(1))) unsigned int*)g,
        (__attribute__((address_space(3))) unsigned int*)l, 16, 0, 0);
}

// ---------------------------------------------------------------------------
// K0: merged prep. y=0..2: transpose {Wv,W1,W2} f32 -> bf16 (N x K); y=3: u
// u[c][h] = sum_d Wk[c][h*64+d] * score_w[h][d]  (bf16; per-head consts cancel
// in softmax so bk/score_b are not needed)
// ---------------------------------------------------------------------------
__global__ __launch_bounds__(256) void prep_all(
    const float* __restrict__ Wk, const float* __restrict__ score_w,
    const float* __restrict__ Wv, const float* __restrict__ W1,
    const float* __restrict__ W2,
    unsigned short* __restrict__ u,
    unsigned short* __restrict__ WvT, unsigned short* __restrict__ W1T,
    unsigned short* __restrict__ W2T) {
    int m = blockIdx.y;
    if (m == 3) {
        int tid = blockIdx.x * 256 + threadIdx.x;
        if (blockIdx.x < 16) {
            int c = tid >> 3, h = tid & 7;
            float s = 0.f;
            #pragma unroll 8
            for (int d = 0; d < D_HEAD; ++d)
                s += Wk[c * D_MODEL + h * D_HEAD + d] * score_w[h * D_HEAD + d];
            u[c * N_HEAD + h] = f2bf(s);
        }
        return;
    }
    const float* in; unsigned short* out; int K, N, tX, tiles;
    if (m == 0)      { in = Wv; out = WvT; K = 512;  N = 512;  tX = 16; tiles = 256;  }
    else if (m == 1) { in = W1; out = W1T; K = 512;  N = 2048; tX = 64; tiles = 1024; }
    else             { in = W2; out = W2T; K = 2048; N = 512;  tX = 16; tiles = 1024; }
    int t = blockIdx.x;
    if (t >= tiles) return;
    int n0 = (t % tX) * 32, k0 = (t / tX) * 32;
    __shared__ float tile[32][33];
    int tx = threadIdx.x & 31, ty = threadIdx.x >> 5;
    #pragma unroll
    for (int i = ty; i < 32; i += 8)
        tile[i][tx] = in[(size_t)(k0 + i) * N + n0 + tx];
    __syncthreads();
    #pragma unroll
    for (int i = ty; i < 32; i += 8)
        out[(size_t)(n0 + i) * K + k0 + tx] = f2bf(tile[tx][i]);
}

// ---------------------------------------------------------------------------
// K1: score+softmax+pool.  256 blocks (1/CU), 1024 threads, 16 batches/block.
// x read ONCE from HBM (reg prefetch one batch ahead), staged bf16 into
// double-buffered LDS.  Raw s_barrier + lgkmcnt-only waits keep the prefetch
// loads in flight across barriers.
// ---------------------------------------------------------------------------
__global__ __launch_bounds__(1024, 4) void score_pool_v3(
    const float* __restrict__ x, const unsigned short* __restrict__ u,
    unsigned short* __restrict__ pooled) {
    __shared__ unsigned short xb[2][NTOK * D_MODEL];   // 2 x 64 KB
    __shared__ float s_attn[NTOK][8];                  // 2 KB, 32B rows (b128-able)
    int tid = threadIdx.x;
    int l = tid & 63, w = tid >> 6;                    // 16 waves
    int b0 = blockIdx.x * 16;

    // lane's u slice: channels l*8..l*8+8, 8 heads each, packed bf16 (32 VGPR)
    u16x8 upk[8];
    {
        const u16x8* up = (const u16x8*)(u + (size_t)l * 64);
        #pragma unroll
        for (int j = 0; j < 8; ++j) upk[j] = up[j];
    }

    // prologue: prefetch batch b0 (32 floats / thread)
    float4 pre[8];
    {
        const float4* g = (const float4*)(x + (size_t)b0 * NTOK * D_MODEL) + tid * 8;
        #pragma unroll
        for (int j = 0; j < 8; ++j) pre[j] = g[j];
    }

    #pragma unroll 1
    for (int i = 0; i < 16; ++i) {
        int cur = i & 1;
        // stage regs -> LDS bf16 (compiler inserts the vmcnt wait for pre[])
        {
            unsigned short* dst = &xb[cur][tid * 32];
            #pragma unroll
            for (int j = 0; j < 4; ++j) {
                float4 a = pre[2 * j], b = pre[2 * j + 1];
                u16x8 o;
                o[0] = f2bf(a.x); o[1] = f2bf(a.y); o[2] = f2bf(a.z); o[3] = f2bf(a.w);
                o[4] = f2bf(b.x); o[5] = f2bf(b.y); o[6] = f2bf(b.z); o[7] = f2bf(b.w);
                *(u16x8*)&dst[j * 8] = o;
            }
        }
        // issue next-batch prefetch (stays in flight across raw barriers)
        if (i < 15) {
            const float4* g = (const float4*)(x + (size_t)(b0 + i + 1) * NTOK * D_MODEL) + tid * 8;
            #pragma unroll
            for (int j = 0; j < 8; ++j) pre[j] = g[j];
        }
        asm volatile("s_waitcnt lgkmcnt(0)" ::: "memory");
        __builtin_amdgcn_s_barrier();

        // phase A: wave w -> tokens w*4..w*4+4; lanes split 512 channels
        #pragma unroll
        for (int r = 0; r < 4; ++r) {
            int n = w * 4 + r;
            u16x8 xr = *(const u16x8*)&xb[cur][n * D_MODEL + l * 8];
            float xv[8];
            #pragma unroll
            for (int q = 0; q < 8; ++q) xv[q] = bf2f(xr[q]);
            float p[8] = {0, 0, 0, 0, 0, 0, 0, 0};
            #pragma unroll
            for (int q = 0; q < 8; ++q)
                #pragma unroll
                for (int h = 0; h < 8; ++h)
                    p[h] += xv[q] * bf2f(upk[q][h]);
            #pragma unroll
            for (int h = 0; h < 8; ++h) p[h] = wave_sum(p[h]);
            if (l == 0) {
                #pragma unroll
                for (int h = 0; h < 8; ++h) s_attn[n][h] = p[h];
            }
        }
        asm volatile("s_waitcnt lgkmcnt(0)" ::: "memory");
        __builtin_amdgcn_s_barrier();

        // phase B: softmax over n (wave 0, lane = token). scores are O(1): no max.
        if (tid < 64) {
            #pragma unroll
            for (int h = 0; h < 8; ++h) {
                float e = __expf(s_attn[tid][h]);
                float den = wave_sum(e);
                s_attn[tid][h] = e / den;
            }
        }
        asm volatile("s_waitcnt lgkmcnt(0)" ::: "memory");
        __builtin_amdgcn_s_barrier();

        // phase C: wave w owns channels [w*32, w*32+32); lane half splits tokens
        {
            int c = (w << 5) + (l & 31);
            int half = l >> 5;
            const unsigned short* xp = &xb[cur][half * 32 * D_MODEL + c];
            float acc[8] = {0, 0, 0, 0, 0, 0, 0, 0};
            #pragma unroll 8
            for (int j = 0; j < 32; ++j) {
                float xf = bf2f(xp[(size_t)j * D_MODEL]);
                f32x4 a0 = *(const f32x4*)&s_attn[half * 32 + j][0];
                f32x4 a1 = *(const f32x4*)&s_attn[half * 32 + j][4];
                acc[0] += a0[0] * xf; acc[1] += a0[1] * xf;
                acc[2] += a0[2] * xf; acc[3] += a0[3] * xf;
                acc[4] += a1[0] * xf; acc[5] += a1[1] * xf;
                acc[6] += a1[2] * xf; acc[7] += a1[3] * xf;
            }
            #pragma unroll
            for (int h = 0; h < 8; ++h) acc[h] += __shfl_xor(acc[h], 32);
            if (half == 0) {
                unsigned short* pb = pooled + (size_t)(b0 + i) * (N_HEAD * D_MODEL);
                #pragma unroll
                for (int h = 0; h < 8; ++h) pb[h * D_MODEL + c] = f2bf(acc[h]);
            }
        }
        // next iter's staging targets xb[1-cur], last read two iters ago; the
        // first barrier of next iter orders it.
    }
}

// ---------------------------------------------------------------------------
// MFMA GEMM (unchanged from round 2): global_load_lds staging, XOR-swizzled
// via pre-swizzled global source, 4 waves (2x2).  MODE 0: per-head, bf16+bias.
// MODE 1: bf16, gelu(+bias).  MODE 2: f32, +bias +residual(bf16).
// ---------------------------------------------------------------------------
template <int BM, int BN, int MODE>
__global__ __launch_bounds__(256) void gemm_mf(
    const unsigned short* __restrict__ A, int lda,
    const unsigned short* __restrict__ BT,
    const float* __restrict__ bias,
    void* __restrict__ Cout, int ldc,
    const unsigned short* __restrict__ res, int K) {
    __shared__ unsigned short Al[BM * 64];
    __shared__ unsigned short Bl[BN * 64];
    int m0 = blockIdx.x * BM;
    int n0;
    const unsigned short* Ap = A;
    const unsigned short* Bp;
    const float* bp;
    if (MODE == 0) {
        int h = blockIdx.y;
        Ap = A + (size_t)h * 512;
        Bp = BT + (size_t)h * 64 * K;
        bp = bias + h * 64;
        n0 = h * 64;
    } else {
        n0 = blockIdx.y * BN;
        Bp = BT + (size_t)n0 * K;
        bp = bias + n0;
    }
    int tid = threadIdx.x, l = tid & 63, w = tid >> 6;
    int lr = l & 15, lq = l >> 4;
    int wm = w >> 1, wn = w & 1;
    constexpr int MR = BM / 32, NR = BN / 32;
    constexpr int AI = BM / 8, BI = BN / 8;

    f32x4 acc[MR][NR];
    #pragma unroll
    for (int mi = 0; mi < MR; ++mi)
        #pragma unroll
        for (int nj = 0; nj < NR; ++nj) acc[mi][nj] = (f32x4){0.f, 0.f, 0.f, 0.f};

    int srow = l >> 3;
    int scol = ((l & 7) ^ ((l >> 3) & 7)) << 3;

    for (int k0 = 0; k0 < K; k0 += 64) {
        #pragma unroll
        for (int j = 0; j < AI / 4; ++j) {
            int ji = w * (AI / 4) + j;
            const unsigned short* src = Ap + (size_t)(m0 + ji * 8 + srow) * lda + k0 + scol;
            gload_lds16(src, &Al[ji * 512]);
        }
        #pragma unroll
        for (int j = 0; j < BI / 4; ++j) {
            int ji = w * (BI / 4) + j;
            const unsigned short* src = Bp + (size_t)(ji * 8 + srow) * K + k0 + scol;
            gload_lds16(src, &Bl[ji * 512]);
        }
        __syncthreads();
        #pragma unroll
        for (int kk = 0; kk < 64; kk += 32) {
            int sw = (kk + lq * 8) ^ ((l & 7) << 3);
            short8 af[MR], bf[NR];
            #pragma unroll
            for (int mi = 0; mi < MR; ++mi)
                af[mi] = *(const short8*)&Al[(wm * (BM / 2) + mi * 16 + lr) * 64 + sw];
            #pragma unroll
            for (int nj = 0; nj < NR; ++nj)
                bf[nj] = *(const short8*)&Bl[(wn * (BN / 2) + nj * 16 + lr) * 64 + sw];
            #pragma unroll
            for (int mi = 0; mi < MR; ++mi)
                #pragma unroll
                for (int nj = 0; nj < NR; ++nj)
                    acc[mi][nj] = __builtin_amdgcn_mfma_f32_16x16x32_bf16(
                        af[mi], bf[nj], acc[mi][nj], 0, 0, 0);
        }
        __syncthreads();
    }

    #pragma unroll
    for (int mi = 0; mi < MR; ++mi) {
        #pragma unroll
        for (int nj = 0; nj < NR; ++nj) {
            #pragma unroll
            for (int j = 0; j < 4; ++j) {
                int row = m0 + wm * (BM / 2) + mi * 16 + lq * 4 + j;
                int nl = wn * (BN / 2) + nj * 16 + lr;
                int col = n0 + nl;
                float v = acc[mi][nj][j] + bp[nl];
                if (MODE == 1) {
                    v = 0.5f * v * (1.0f + erff(v * 0.70710678118654752f));
                }
                if (MODE == 2) {
                    v += bf2f(res[(size_t)row * 512 + col]);
                    ((float*)Cout)[(size_t)row * ldc + col] = v;
                } else {
                    ((unsigned short*)Cout)[(size_t)row * ldc + col] = f2bf(v);
                }
            }
        }
    }
}

// ---------------------------------------------------------------------------
// K5: in-place LayerNorm over 512, one wave per row
// ---------------------------------------------------------------------------
__global__ __launch_bounds__(256) void ln_kernel(
    float* __restrict__ y, const float* __restrict__ g, const float* __restrict__ bta) {
    int row = blockIdx.x * 4 + (threadIdx.x >> 6);
    int l = threadIdx.x & 63;
    float* yp = y + (size_t)row * D_MODEL;
    float4 v0 = *(const float4*)(yp + l * 8);
    float4 v1 = *(const float4*)(yp + l * 8 + 4);
    float vv[8] = {v0.x, v0.y, v0.z, v0.w, v1.x, v1.y, v1.z, v1.w};
    float s = 0.f;
    #pragma unroll
    for (int i = 0; i < 8; ++i) s += vv[i];
    s = wave_sum(s);
    float mean = s * (1.f / 512.f);
    float q = 0.f;
    #pragma unroll
    for (int i = 0; i < 8; ++i) { float d = vv[i] - mean; q += d * d; }
    q = wave_sum(q);
    float rstd = rsqrtf(q * (1.f / 512.f) + 1e-5f);
    float4 g0 = *(const float4*)(g + l * 8);
    float4 g1 = *(const float4*)(g + l * 8 + 4);
    float4 b0 = *(const float4*)(bta + l * 8);
    float4 b1 = *(const float4*)(bta + l * 8 + 4);
    float gv[8] = {g0.x, g0.y, g0.z, g0.w, g1.x, g1.y, g1.z, g1.w};
    float bv[8] = {b0.x, b0.y, b0.z, b0.w, b1.x, b1.y, b1.z, b1.w};
    float ov[8];
    #pragma unroll
    for (int i = 0; i < 8; ++i) ov[i] = (vv[i] - mean) * rstd * gv[i] + bv[i];
    float4 o0 = {ov[0], ov[1], ov[2], ov[3]};
    float4 o1 = {ov[4], ov[5], ov[6], ov[7]};
    *(float4*)(yp + l * 8) = o0;
    *(float4*)(yp + l * 8 + 4) = o1;
}

extern "C" void kernel_launch(void* const* d_in, const int* in_sizes, int n_in,
                              void* d_out, int out_size, void* d_ws, size_t ws_size,
                              hipStream_t stream) {
    const float* x       = (const float*)d_in[0];
    const float* Wk      = (const float*)d_in[1];
    const float* Wv      = (const float*)d_in[3];
    const float* bv      = (const float*)d_in[4];
    const float* score_w = (const float*)d_in[5];
    const float* W1      = (const float*)d_in[7];
    const float* b1      = (const float*)d_in[8];
    const float* W2      = (const float*)d_in[9];
    const float* b2      = (const float*)d_in[10];
    const float* ln_g    = (const float*)d_in[11];
    const float* ln_b    = (const float*)d_in[12];
    float* out = (float*)d_out;

    char* ws = (char*)d_ws;
    size_t off = 0;
    auto alloc = [&](size_t sz) {
        void* p = ws + off;
        off = (off + sz + 1023) & ~(size_t)1023;
        return p;
    };
    unsigned short* u   = (unsigned short*)alloc((size_t)D_MODEL * N_HEAD * 2);
    unsigned short* WvT = (unsigned short*)alloc((size_t)512 * 512 * 2);
    unsigned short* W1T = (unsigned short*)alloc((size_t)2048 * 512 * 2);
    unsigned short* W2T = (unsigned short*)alloc((size_t)512 * 2048 * 2);
    unsigned short* pooled = (unsigned short*)alloc((size_t)BATCH * N_HEAD * D_MODEL * 2);
    unsigned short* feat   = (unsigned short*)alloc((size_t)BATCH * D_MODEL * 2);
    unsigned short* Hbuf   = (unsigned short*)alloc((size_t)BATCH * D_HIDDEN * 2);

    prep_all<<<dim3(1024, 4), dim3(256), 0, stream>>>(
        Wk, score_w, Wv, W1, W2, u, WvT, W1T, W2T);
    score_pool_v3<<<dim3(256), dim3(1024), 0, stream>>>(x, u, pooled);
    // proj: feature = pooled @ blockdiag(Wv per head) + bv
    gemm_mf<128, 64, 0><<<dim3(32, 8), dim3(256), 0, stream>>>(
        pooled, N_HEAD * D_MODEL, WvT, bv, (void*)feat, D_MODEL,
        (const unsigned short*)nullptr, 512);
    // ffn1: H = gelu(feature @ W1 + b1)
    gemm_mf<128, 128, 1><<<dim3(32, 16), dim3(256), 0, stream>>>(
        feat, D_MODEL, W1T, b1, (void*)Hbuf, D_HIDDEN,
        (const unsigned short*)nullptr, 512);
    // ffn2: y = H @ W2 + b2 + feature  (f32 -> d_out)
    gemm_mf<64, 128, 2><<<dim3(64, 4), dim3(256), 0, stream>>>(
        Hbuf, D_HIDDEN, W2T, b2, (void*)out, D_MODEL, feat, 2048);
    ln_kernel<<<dim3(1024), dim3(256), 0, stream>>>(out, ln_g, ln_b);
}

// Round 4
// 305.353 us; speedup vs baseline: 1.3312x; 1.3312x over previous
//
#include <hip/hip_runtime.h>
#include <hip/hip_bf16.h>

#define N_HEAD 8
#define D_MODEL 512
#define D_HEAD 64
#define D_HIDDEN 2048
#define NTOK 64
#define BATCH 4096

typedef __attribute__((ext_vector_type(4))) float f32x4;
typedef __attribute__((ext_vector_type(8))) short short8;
typedef __attribute__((ext_vector_type(8))) unsigned short u16x8;
typedef __attribute__((ext_vector_type(4))) unsigned short u16x4;

__device__ __forceinline__ float bf2f(unsigned short u) {
    return __uint_as_float(((unsigned int)u) << 16);
}
__device__ __forceinline__ unsigned short f2bf(float f) {
    unsigned int b = __float_as_uint(f);
    b += 0x7fffu + ((b >> 16) & 1u);
    return (unsigned short)(b >> 16);
}
__device__ __forceinline__ float wave_sum(float v) {
    v += __shfl_xor(v, 32); v += __shfl_xor(v, 16); v += __shfl_xor(v, 8);
    v += __shfl_xor(v, 4);  v += __shfl_xor(v, 2);  v += __shfl_xor(v, 1);
    return v;
}
__device__ __forceinline__ void gload_lds16(const void* g, void* l) {
    __builtin_amdgcn_global_load_lds(
        (const __attribute__((address_space(1))) unsigned int*)g,
        (__attribute__((address_space(3))) unsigned int*)l, 16, 0, 0);
}

// ---------------------------------------------------------------------------
// K0: merged prep. y=0..2: transpose {Wv,W1,W2} f32 -> bf16 (N x K);
// y=3: uT[16][512] bf16 with uT[h][c] = sum_d Wk[c][h*64+d]*score_w[h][d],
// heads 8..15 zero (per-head consts cancel in softmax; bk/score_b unused).
// ---------------------------------------------------------------------------
__global__ __launch_bounds__(256) void prep_all(
    const float* __restrict__ Wk, const float* __restrict__ score_w,
    const float* __restrict__ Wv, const float* __restrict__ W1,
    const float* __restrict__ W2,
    unsigned short* __restrict__ uT,
    unsigned short* __restrict__ WvT, unsigned short* __restrict__ W1T,
    unsigned short* __restrict__ W2T) {
    int m = blockIdx.y;
    if (m == 3) {
        int idx = blockIdx.x * 256 + threadIdx.x;
        if (idx < 16 * 512) {
            int h = idx & 15, c = idx >> 4;
            float s = 0.f;
            if (h < 8) {
                #pragma unroll 8
                for (int d = 0; d < D_HEAD; ++d)
                    s += Wk[c * D_MODEL + h * D_HEAD + d] * score_w[h * D_HEAD + d];
            }
            uT[h * D_MODEL + c] = f2bf(s);
        }
        return;
    }
    const float* in; unsigned short* out; int K, N, tX, tiles;
    if (m == 0)      { in = Wv; out = WvT; K = 512;  N = 512;  tX = 16; tiles = 256;  }
    else if (m == 1) { in = W1; out = W1T; K = 512;  N = 2048; tX = 64; tiles = 1024; }
    else             { in = W2; out = W2T; K = 2048; N = 512;  tX = 16; tiles = 1024; }
    int t = blockIdx.x;
    if (t >= tiles) return;
    int n0 = (t % tX) * 32, k0 = (t / tX) * 32;
    __shared__ float tile[32][33];
    int tx = threadIdx.x & 31, ty = threadIdx.x >> 5;
    #pragma unroll
    for (int i = ty; i < 32; i += 8)
        tile[i][tx] = in[(size_t)(k0 + i) * N + n0 + tx];
    __syncthreads();
    #pragma unroll
    for (int i = ty; i < 32; i += 8)
        out[(size_t)(n0 + i) * K + k0 + tx] = f2bf(tile[tx][i]);
}

// ---------------------------------------------------------------------------
// K1 v4: score+softmax+pool. 512 blocks (2/CU), 512 threads (8 waves),
// 8 batches/block.  Per batch: reg-prefetch -> swizzled bf16 LDS (x read ONCE
// from HBM); scores via MFMA S^T = u^T @ x^T (waves 0-3, u-frags persistent
// in registers); softmax with 4 shfl_xor + tiny LDS combine; pool from LDS
// (thread = channel-pair, split over token halves, bf16 LDS cross-half add).
// Raw s_barrier + lgkmcnt-only waits keep prefetch loads in flight.
// ---------------------------------------------------------------------------
__global__ __launch_bounds__(512, 4) void score_pool_v4(
    const float* __restrict__ x, const unsigned short* __restrict__ uT,
    unsigned short* __restrict__ pooled) {
    __shared__ unsigned short xl[NTOK * D_MODEL];   // 64 KB, XOR-swizzled rows
    __shared__ unsigned short attn_l[NTOK * 8];     // 1 KB  [n][h] bf16
    __shared__ float zred[4][16];                   // 256 B
    __shared__ unsigned short red[256][16];         // 8 KB  cross-half partials

    const int tid = threadIdx.x;
    const int l = tid & 63, w = tid >> 6;
    const int hg = l >> 4;          // 0..3 : k-slice group / head group
    const int lr = l & 15;          // row/col-in-tile lane id

    // persistent A-fragments of u^T: lane holds uT[lr][ks*32 + hg*8 .. +8]
    short8 ufrag[16];
    {
        const unsigned short* up = uT + lr * D_MODEL + hg * 8;
        #pragma unroll
        for (int ks = 0; ks < 16; ++ks)
            ufrag[ks] = *(const short8*)(up + ks * 32);
    }

    const int b0 = blockIdx.x * 8;

    // prologue: prefetch batch b0 (64 floats / thread)
    float4 pre[16];
    {
        const float4* g = (const float4*)(x + (size_t)b0 * (NTOK * D_MODEL));
        #pragma unroll
        for (int j = 0; j < 16; ++j) pre[j] = g[j * 512 + tid];
    }

    #pragma unroll 1
    for (int i = 0; i < 8; ++i) {
        // ---- stage: regs -> swizzled bf16 LDS ----
        {
            int nb = tid >> 7;               // 0..3
            int c = (tid & 127) * 4;
            #pragma unroll
            for (int j = 0; j < 16; ++j) {
                int n = j * 4 + nb;
                int idx = n * D_MODEL + (c ^ ((n & 7) << 3));
                float4 v = pre[j];
                u16x4 o = {f2bf(v.x), f2bf(v.y), f2bf(v.z), f2bf(v.w)};
                *(u16x4*)&xl[idx] = o;
            }
        }
        // issue next-batch prefetch (in flight across all barriers below)
        if (i < 7) {
            const float4* g = (const float4*)(x + (size_t)(b0 + i + 1) * (NTOK * D_MODEL));
            #pragma unroll
            for (int j = 0; j < 16; ++j) pre[j] = g[j * 512 + tid];
        }
        asm volatile("s_waitcnt lgkmcnt(0)" ::: "memory");
        __builtin_amdgcn_s_barrier();

        // ---- phase A: S^T[h, n] via MFMA (waves 0-3; wave w = token tile) ----
        float ev[4];
        if (w < 4) {
            f32x4 sacc = {0.f, 0.f, 0.f, 0.f};
            const int tok = w * 16 + lr;
            const int rbase = tok * D_MODEL;
            const int rsw = (tok & 7) << 3;
            #pragma unroll
            for (int ks = 0; ks < 16; ++ks) {
                short8 xf = *(const short8*)&xl[rbase + ((ks * 32 + hg * 8) ^ rsw)];
                sacc = __builtin_amdgcn_mfma_f32_16x16x32_bf16(ufrag[ks], xf, sacc, 0, 0, 0);
            }
            // exp (scores are O(0.1): no max subtraction needed) + 16-token reduce
            float zsum[4];
            #pragma unroll
            for (int j = 0; j < 4; ++j) {
                float e = __expf(sacc[j]);
                ev[j] = e;
                e += __shfl_xor(e, 1); e += __shfl_xor(e, 2);
                e += __shfl_xor(e, 4); e += __shfl_xor(e, 8);
                zsum[j] = e;
            }
            if (lr == 0) {
                f32x4 zz = {zsum[0], zsum[1], zsum[2], zsum[3]};
                *(f32x4*)&zred[w][hg * 4] = zz;
            }
        }
        asm volatile("s_waitcnt lgkmcnt(0)" ::: "memory");
        __builtin_amdgcn_s_barrier();

        // ---- phase B: finish softmax, write attn (bf16) ----
        if (w < 4 && hg < 2) {
            f32x4 z0 = *(const f32x4*)&zred[0][hg * 4];
            f32x4 z1 = *(const f32x4*)&zred[1][hg * 4];
            f32x4 z2 = *(const f32x4*)&zred[2][hg * 4];
            f32x4 z3 = *(const f32x4*)&zred[3][hg * 4];
            int tok = w * 16 + lr;
            u16x4 a;
            #pragma unroll
            for (int j = 0; j < 4; ++j) {
                float zt = z0[j] + z1[j] + z2[j] + z3[j];
                a[j] = f2bf(ev[j] * __frcp_rn(zt));
            }
            *(u16x4*)&attn_l[tok * 8 + hg * 4] = a;
        }
        asm volatile("s_waitcnt lgkmcnt(0)" ::: "memory");
        __builtin_amdgcn_s_barrier();

        // ---- phase C: pooled[h][c] = sum_n attn[n][h] * x[n][c] ----
        {
            const int c2 = (tid & 255) * 2;
            const int half = tid >> 8;
            float acc[16];
            #pragma unroll
            for (int k = 0; k < 16; ++k) acc[k] = 0.f;
            const int n0 = half * 32;
            #pragma unroll 8
            for (int n = n0; n < n0 + 32; ++n) {
                unsigned int xw = *(const unsigned int*)&xl[n * D_MODEL + (c2 ^ ((n & 7) << 3))];
                float xa = __uint_as_float(xw << 16);
                float xb = __uint_as_float(xw & 0xffff0000u);
                u16x8 ar = *(const u16x8*)&attn_l[n * 8];
                #pragma unroll
                for (int h = 0; h < 8; ++h) {
                    float a = bf2f(ar[h]);
                    acc[h * 2 + 0] += a * xa;
                    acc[h * 2 + 1] += a * xb;
                }
            }
            if (half) {
                u16x8 r0, r1;
                #pragma unroll
                for (int k = 0; k < 8; ++k) { r0[k] = f2bf(acc[k]); r1[k] = f2bf(acc[8 + k]); }
                *(u16x8*)&red[tid & 255][0] = r0;
                *(u16x8*)&red[tid & 255][8] = r1;
            }
            asm volatile("s_waitcnt lgkmcnt(0)" ::: "memory");
            __builtin_amdgcn_s_barrier();
            if (!half) {
                u16x8 r0 = *(const u16x8*)&red[tid & 255][0];
                u16x8 r1 = *(const u16x8*)&red[tid & 255][8];
                unsigned short* pb = pooled + (size_t)(b0 + i) * (N_HEAD * D_MODEL);
                #pragma unroll
                for (int h = 0; h < 8; ++h) {
                    float v0 = acc[h * 2 + 0] + bf2f(h < 4 ? r0[h * 2] : r1[h * 2 - 8]);
                    float v1 = acc[h * 2 + 1] + bf2f(h < 4 ? r0[h * 2 + 1] : r1[h * 2 - 7]);
                    unsigned int pk = (unsigned int)f2bf(v0) | ((unsigned int)f2bf(v1) << 16);
                    *(unsigned int*)(pb + h * D_MODEL + c2) = pk;
                }
            }
        }
        // xl is re-staged next iteration: order phase-C reads before it
        asm volatile("s_waitcnt lgkmcnt(0)" ::: "memory");
        __builtin_amdgcn_s_barrier();
    }
}

// ---------------------------------------------------------------------------
// MFMA GEMM (unchanged): global_load_lds staging, XOR-swizzled via
// pre-swizzled global source, 4 waves (2x2).  MODE 0: per-head, bf16+bias.
// MODE 1: bf16, gelu(+bias).  MODE 2: f32, +bias +residual(bf16).
// ---------------------------------------------------------------------------
template <int BM, int BN, int MODE>
__global__ __launch_bounds__(256) void gemm_mf(
    const unsigned short* __restrict__ A, int lda,
    const unsigned short* __restrict__ BT,
    const float* __restrict__ bias,
    void* __restrict__ Cout, int ldc,
    const unsigned short* __restrict__ res, int K) {
    __shared__ unsigned short Al[BM * 64];
    __shared__ unsigned short Bl[BN * 64];
    int m0 = blockIdx.x * BM;
    int n0;
    const unsigned short* Ap = A;
    const unsigned short* Bp;
    const float* bp;
    if (MODE == 0) {
        int h = blockIdx.y;
        Ap = A + (size_t)h * 512;
        Bp = BT + (size_t)h * 64 * K;
        bp = bias + h * 64;
        n0 = h * 64;
    } else {
        n0 = blockIdx.y * BN;
        Bp = BT + (size_t)n0 * K;
        bp = bias + n0;
    }
    int tid = threadIdx.x, l = tid & 63, w = tid >> 6;
    int lr = l & 15, lq = l >> 4;
    int wm = w >> 1, wn = w & 1;
    constexpr int MR = BM / 32, NR = BN / 32;
    constexpr int AI = BM / 8, BI = BN / 8;

    f32x4 acc[MR][NR];
    #pragma unroll
    for (int mi = 0; mi < MR; ++mi)
        #pragma unroll
        for (int nj = 0; nj < NR; ++nj) acc[mi][nj] = (f32x4){0.f, 0.f, 0.f, 0.f};

    int srow = l >> 3;
    int scol = ((l & 7) ^ ((l >> 3) & 7)) << 3;

    for (int k0 = 0; k0 < K; k0 += 64) {
        #pragma unroll
        for (int j = 0; j < AI / 4; ++j) {
            int ji = w * (AI / 4) + j;
            const unsigned short* src = Ap + (size_t)(m0 + ji * 8 + srow) * lda + k0 + scol;
            gload_lds16(src, &Al[ji * 512]);
        }
        #pragma unroll
        for (int j = 0; j < BI / 4; ++j) {
            int ji = w * (BI / 4) + j;
            const unsigned short* src = Bp + (size_t)(ji * 8 + srow) * K + k0 + scol;
            gload_lds16(src, &Bl[ji * 512]);
        }
        __syncthreads();
        #pragma unroll
        for (int kk = 0; kk < 64; kk += 32) {
            int sw = (kk + lq * 8) ^ ((l & 7) << 3);
            short8 af[MR], bf[NR];
            #pragma unroll
            for (int mi = 0; mi < MR; ++mi)
                af[mi] = *(const short8*)&Al[(wm * (BM / 2) + mi * 16 + lr) * 64 + sw];
            #pragma unroll
            for (int nj = 0; nj < NR; ++nj)
                bf[nj] = *(const short8*)&Bl[(wn * (BN / 2) + nj * 16 + lr) * 64 + sw];
            #pragma unroll
            for (int mi = 0; mi < MR; ++mi)
                #pragma unroll
                for (int nj = 0; nj < NR; ++nj)
                    acc[mi][nj] = __builtin_amdgcn_mfma_f32_16x16x32_bf16(
                        af[mi], bf[nj], acc[mi][nj], 0, 0, 0);
        }
        __syncthreads();
    }

    #pragma unroll
    for (int mi = 0; mi < MR; ++mi) {
        #pragma unroll
        for (int nj = 0; nj < NR; ++nj) {
            #pragma unroll
            for (int j = 0; j < 4; ++j) {
                int row = m0 + wm * (BM / 2) + mi * 16 + lq * 4 + j;
                int nl = wn * (BN / 2) + nj * 16 + lr;
                int col = n0 + nl;
                float v = acc[mi][nj][j] + bp[nl];
                if (MODE == 1) {
                    v = 0.5f * v * (1.0f + erff(v * 0.70710678118654752f));
                }
                if (MODE == 2) {
                    v += bf2f(res[(size_t)row * 512 + col]);
                    ((float*)Cout)[(size_t)row * ldc + col] = v;
                } else {
                    ((unsigned short*)Cout)[(size_t)row * ldc + col] = f2bf(v);
                }
            }
        }
    }
}

// ---------------------------------------------------------------------------
// K5: in-place LayerNorm over 512, one wave per row
// ---------------------------------------------------------------------------
__global__ __launch_bounds__(256) void ln_kernel(
    float* __restrict__ y, const float* __restrict__ g, const float* __restrict__ bta) {
    int row = blockIdx.x * 4 + (threadIdx.x >> 6);
    int l = threadIdx.x & 63;
    float* yp = y + (size_t)row * D_MODEL;
    float4 v0 = *(const float4*)(yp + l * 8);
    float4 v1 = *(const float4*)(yp + l * 8 + 4);
    float vv[8] = {v0.x, v0.y, v0.z, v0.w, v1.x, v1.y, v1.z, v1.w};
    float s = 0.f;
    #pragma unroll
    for (int i = 0; i < 8; ++i) s += vv[i];
    s = wave_sum(s);
    float mean = s * (1.f / 512.f);
    float q = 0.f;
    #pragma unroll
    for (int i = 0; i < 8; ++i) { float d = vv[i] - mean; q += d * d; }
    q = wave_sum(q);
    float rstd = rsqrtf(q * (1.f / 512.f) + 1e-5f);
    float4 g0 = *(const float4*)(g + l * 8);
    float4 g1 = *(const float4*)(g + l * 8 + 4);
    float4 b0 = *(const float4*)(bta + l * 8);
    float4 b1 = *(const float4*)(bta + l * 8 + 4);
    float gv[8] = {g0.x, g0.y, g0.z, g0.w, g1.x, g1.y, g1.z, g1.w};
    float bv[8] = {b0.x, b0.y, b0.z, b0.w, b1.x, b1.y, b1.z, b1.w};
    float ov[8];
    #pragma unroll
    for (int i = 0; i < 8; ++i) ov[i] = (vv[i] - mean) * rstd * gv[i] + bv[i];
    float4 o0 = {ov[0], ov[1], ov[2], ov[3]};
    float4 o1 = {ov[4], ov[5], ov[6], ov[7]};
    *(float4*)(yp + l * 8) = o0;
    *(float4*)(yp + l * 8 + 4) = o1;
}

extern "C" void kernel_launch(void* const* d_in, const int* in_sizes, int n_in,
                              void* d_out, int out_size, void* d_ws, size_t ws_size,
                              hipStream_t stream) {
    const float* x       = (const float*)d_in[0];
    const float* Wk      = (const float*)d_in[1];
    const float* Wv      = (const float*)d_in[3];
    const float* bv      = (const float*)d_in[4];
    const float* score_w = (const float*)d_in[5];
    const float* W1      = (const float*)d_in[7];
    const float* b1      = (const float*)d_in[8];
    const float* W2      = (const float*)d_in[9];
    const float* b2      = (const float*)d_in[10];
    const float* ln_g    = (const float*)d_in[11];
    const float* ln_b    = (const float*)d_in[12];
    float* out = (float*)d_out;

    char* ws = (char*)d_ws;
    size_t off = 0;
    auto alloc = [&](size_t sz) {
        void* p = ws + off;
        off = (off + sz + 1023) & ~(size_t)1023;
        return p;
    };
    unsigned short* uT  = (unsigned short*)alloc((size_t)16 * D_MODEL * 2);
    unsigned short* WvT = (unsigned short*)alloc((size_t)512 * 512 * 2);
    unsigned short* W1T = (unsigned short*)alloc((size_t)2048 * 512 * 2);
    unsigned short* W2T = (unsigned short*)alloc((size_t)512 * 2048 * 2);
    unsigned short* pooled = (unsigned short*)alloc((size_t)BATCH * N_HEAD * D_MODEL * 2);
    unsigned short* feat   = (unsigned short*)alloc((size_t)BATCH * D_MODEL * 2);
    unsigned short* Hbuf   = (unsigned short*)alloc((size_t)BATCH * D_HIDDEN * 2);

    prep_all<<<dim3(1024, 4), dim3(256), 0, stream>>>(
        Wk, score_w, Wv, W1, W2, uT, WvT, W1T, W2T);
    score_pool_v4<<<dim3(512), dim3(512), 0, stream>>>(x, uT, pooled);
    // proj: feature = pooled @ blockdiag(Wv per head) + bv
    gemm_mf<128, 64, 0><<<dim3(32, 8), dim3(256), 0, stream>>>(
        pooled, N_HEAD * D_MODEL, WvT, bv, (void*)feat, D_MODEL,
        (const unsigned short*)nullptr, 512);
    // ffn1: H = gelu(feature @ W1 + b1)
    gemm_mf<128, 128, 1><<<dim3(32, 16), dim3(256), 0, stream>>>(
        feat, D_MODEL, W1T, b1, (void*)Hbuf, D_HIDDEN,
        (const unsigned short*)nullptr, 512);
    // ffn2: y = H @ W2 + b2 + feature  (f32 -> d_out)
    gemm_mf<64, 128, 2><<<dim3(64, 4), dim3(256), 0, stream>>>(
        Hbuf, D_HIDDEN, W2T, b2, (void*)out, D_MODEL, feat, 2048);
    ln_kernel<<<dim3(1024), dim3(256), 0, stream>>>(out, ln_g, ln_b);
}

// Round 5
// 300.620 us; speedup vs baseline: 1.3522x; 1.0157x over previous
//
#include <hip/hip_runtime.h>
#include <hip/hip_bf16.h>

#define N_HEAD 8
#define D_MODEL 512
#define D_HEAD 64
#define D_HIDDEN 2048
#define NTOK 64
#define BATCH 4096

typedef __attribute__((ext_vector_type(4))) float f32x4;
typedef __attribute__((ext_vector_type(8))) short short8;
typedef __attribute__((ext_vector_type(8))) unsigned short u16x8;
typedef __attribute__((ext_vector_type(4))) unsigned short u16x4;

__device__ __forceinline__ float bf2f(unsigned short u) {
    return __uint_as_float(((unsigned int)u) << 16);
}
__device__ __forceinline__ unsigned short f2bf(float f) {
    unsigned int b = __float_as_uint(f);
    b += 0x7fffu + ((b >> 16) & 1u);
    return (unsigned short)(b >> 16);
}
__device__ __forceinline__ float wave_sum(float v) {
    v += __shfl_xor(v, 32); v += __shfl_xor(v, 16); v += __shfl_xor(v, 8);
    v += __shfl_xor(v, 4);  v += __shfl_xor(v, 2);  v += __shfl_xor(v, 1);
    return v;
}
__device__ __forceinline__ void gload_lds16(const void* g, void* l) {
    __builtin_amdgcn_global_load_lds(
        (const __attribute__((address_space(1))) unsigned int*)g,
        (__attribute__((address_space(3))) unsigned int*)l, 16, 0, 0);
}

// ---------------------------------------------------------------------------
// K0: merged prep. y=0..2: transpose {Wv,W1,W2} f32 -> bf16 (N x K);
// y=3: uT[16][512] bf16 with uT[h][c] = sum_d Wk[c][h*64+d]*score_w[h][d],
// heads 8..15 zero (per-head consts cancel in softmax; bk/score_b unused).
// ---------------------------------------------------------------------------
__global__ __launch_bounds__(256) void prep_all(
    const float* __restrict__ Wk, const float* __restrict__ score_w,
    const float* __restrict__ Wv, const float* __restrict__ W1,
    const float* __restrict__ W2,
    unsigned short* __restrict__ uT,
    unsigned short* __restrict__ WvT, unsigned short* __restrict__ W1T,
    unsigned short* __restrict__ W2T) {
    int m = blockIdx.y;
    if (m == 3) {
        int idx = blockIdx.x * 256 + threadIdx.x;
        if (idx < 16 * 512) {
            int h = idx & 15, c = idx >> 4;
            float s = 0.f;
            if (h < 8) {
                #pragma unroll 8
                for (int d = 0; d < D_HEAD; ++d)
                    s += Wk[c * D_MODEL + h * D_HEAD + d] * score_w[h * D_HEAD + d];
            }
            uT[h * D_MODEL + c] = f2bf(s);
        }
        return;
    }
    const float* in; unsigned short* out; int K, N, tX, tiles;
    if (m == 0)      { in = Wv; out = WvT; K = 512;  N = 512;  tX = 16; tiles = 256;  }
    else if (m == 1) { in = W1; out = W1T; K = 512;  N = 2048; tX = 64; tiles = 1024; }
    else             { in = W2; out = W2T; K = 2048; N = 512;  tX = 16; tiles = 1024; }
    int t = blockIdx.x;
    if (t >= tiles) return;
    int n0 = (t % tX) * 32, k0 = (t / tX) * 32;
    __shared__ float tile[32][33];
    int tx = threadIdx.x & 31, ty = threadIdx.x >> 5;
    #pragma unroll
    for (int i = ty; i < 32; i += 8)
        tile[i][tx] = in[(size_t)(k0 + i) * N + n0 + tx];
    __syncthreads();
    #pragma unroll
    for (int i = ty; i < 32; i += 8)
        out[(size_t)(n0 + i) * K + k0 + tx] = f2bf(tile[tx][i]);
}

// ---------------------------------------------------------------------------
// K1 v5: score+softmax+pool. 512 blocks (2/CU via 76 KB LDS), 512 threads,
// 8 batches/block.  vs v4: u-fragments moved to LDS (frees 64 VGPR -> no
// spill), attn kept f32 (phase C reads b128 broadcast), phase C split
// channel-pair x head-half over all 64 tokens (no cross-half reduction).
// x read ONCE from HBM; prefetch regs stay in flight across raw s_barriers
// (lgkmcnt-only waits).
// ---------------------------------------------------------------------------
__global__ __launch_bounds__(512, 4) void score_pool_v5(
    const float* __restrict__ x, const unsigned short* __restrict__ uT,
    unsigned short* __restrict__ pooled) {
    __shared__ unsigned short xl[NTOK * D_MODEL];   // 64 KB, XOR-swizzled rows
    __shared__ unsigned short ul[8 * D_MODEL];      // 8 KB, swizzled uT rows 0..7
    __shared__ float attn_l[NTOK * 8];              // 2 KB  [n][h] f32
    __shared__ float zred[4][16];                   // 256 B

    const int tid = threadIdx.x;
    const int l = tid & 63, w = tid >> 6;
    const int hg = l >> 4;          // 0..3 : k-subgroup / head group
    const int lr = l & 15;          // row/col-in-tile lane id

    // copy u^T rows 0..7 into LDS (swizzled like xl rows)
    {
        int r = tid >> 6;            // 0..7
        int c8 = (tid & 63) * 8;
        u16x8 v = *(const u16x8*)(uT + r * D_MODEL + c8);
        *(u16x8*)&ul[r * D_MODEL + (c8 ^ (r << 3))] = v;
    }

    const int b0 = blockIdx.x * 8;

    // prologue: prefetch batch b0 (64 floats / thread)
    float4 pre[16];
    {
        const float4* g = (const float4*)(x + (size_t)b0 * (NTOK * D_MODEL));
        #pragma unroll
        for (int j = 0; j < 16; ++j) pre[j] = g[j * 512 + tid];
    }

    #pragma unroll 1
    for (int i = 0; i < 8; ++i) {
        // ---- stage: regs -> swizzled bf16 LDS ----
        {
            int nb = tid >> 7;               // 0..3
            int c = (tid & 127) * 4;
            #pragma unroll
            for (int j = 0; j < 16; ++j) {
                int n = j * 4 + nb;
                int idx = n * D_MODEL + (c ^ ((n & 7) << 3));
                float4 v = pre[j];
                u16x4 o = {f2bf(v.x), f2bf(v.y), f2bf(v.z), f2bf(v.w)};
                *(u16x4*)&xl[idx] = o;
            }
        }
        // issue next-batch prefetch (in flight across all barriers below)
        if (i < 7) {
            const float4* g = (const float4*)(x + (size_t)(b0 + i + 1) * (NTOK * D_MODEL));
            #pragma unroll
            for (int j = 0; j < 16; ++j) pre[j] = g[j * 512 + tid];
        }
        asm volatile("s_waitcnt lgkmcnt(0)" ::: "memory");
        __builtin_amdgcn_s_barrier();

        // ---- phase A: S^T[h, n] via MFMA (waves 0-3; wave w = 16-token tile) ----
        float ev[4];
        if (w < 4) {
            f32x4 sacc = {0.f, 0.f, 0.f, 0.f};
            const int tok = w * 16 + lr;
            const int rbase = tok * D_MODEL;
            const int rsw = (tok & 7) << 3;
            const int usw = (lr & 7) << 3;
            #pragma unroll
            for (int ks = 0; ks < 16; ++ks) {
                int off = ks * 32 + hg * 8;
                short8 uf;
                if (lr < 8) uf = *(const short8*)&ul[lr * D_MODEL + (off ^ usw)];
                else        uf = (short8){0, 0, 0, 0, 0, 0, 0, 0};
                short8 xf = *(const short8*)&xl[rbase + (off ^ rsw)];
                sacc = __builtin_amdgcn_mfma_f32_16x16x32_bf16(uf, xf, sacc, 0, 0, 0);
            }
            // exp (scores are O(0.1): no max subtraction) + 16-token partial Z
            float zsum[4];
            #pragma unroll
            for (int j = 0; j < 4; ++j) {
                float e = __expf(sacc[j]);
                ev[j] = e;
                e += __shfl_xor(e, 1); e += __shfl_xor(e, 2);
                e += __shfl_xor(e, 4); e += __shfl_xor(e, 8);
                zsum[j] = e;
            }
            if (lr == 0) {
                f32x4 zz = {zsum[0], zsum[1], zsum[2], zsum[3]};
                *(f32x4*)&zred[w][hg * 4] = zz;
            }
        }
        asm volatile("s_waitcnt lgkmcnt(0)" ::: "memory");
        __builtin_amdgcn_s_barrier();

        // ---- phase B: finish softmax, write attn (f32) ----
        if (w < 4 && hg < 2) {
            f32x4 z0 = *(const f32x4*)&zred[0][hg * 4];
            f32x4 z1 = *(const f32x4*)&zred[1][hg * 4];
            f32x4 z2 = *(const f32x4*)&zred[2][hg * 4];
            f32x4 z3 = *(const f32x4*)&zred[3][hg * 4];
            int tok = w * 16 + lr;
            f32x4 a;
            #pragma unroll
            for (int j = 0; j < 4; ++j) {
                float zt = z0[j] + z1[j] + z2[j] + z3[j];
                a[j] = ev[j] * __frcp_rn(zt);
            }
            *(f32x4*)&attn_l[tok * 8 + hg * 4] = a;
        }
        asm volatile("s_waitcnt lgkmcnt(0)" ::: "memory");
        __builtin_amdgcn_s_barrier();

        // ---- phase C: pooled[h][c] = sum_n attn[n][h] * x[n][c] ----
        {
            const int c2 = (tid & 255) * 2;
            const int hh = tid >> 8;            // 0/1: heads hh*4..hh*4+3
            float acc[8];
            #pragma unroll
            for (int k = 0; k < 8; ++k) acc[k] = 0.f;
            #pragma unroll 8
            for (int n = 0; n < 64; ++n) {
                unsigned int xw = *(const unsigned int*)&xl[n * D_MODEL + (c2 ^ ((n & 7) << 3))];
                float xa = __uint_as_float(xw << 16);
                float xb = __uint_as_float(xw & 0xffff0000u);
                f32x4 ar = *(const f32x4*)&attn_l[n * 8 + hh * 4];
                #pragma unroll
                for (int j = 0; j < 4; ++j) {
                    acc[j * 2 + 0] += ar[j] * xa;
                    acc[j * 2 + 1] += ar[j] * xb;
                }
            }
            unsigned short* pb = pooled + (size_t)(b0 + i) * (N_HEAD * D_MODEL);
            #pragma unroll
            for (int j = 0; j < 4; ++j) {
                int h = hh * 4 + j;
                unsigned int pk = (unsigned int)f2bf(acc[j * 2]) |
                                  ((unsigned int)f2bf(acc[j * 2 + 1]) << 16);
                *(unsigned int*)(pb + h * D_MODEL + c2) = pk;
            }
        }
        // order phase-C LDS reads before next iteration's staging overwrite
        asm volatile("s_waitcnt lgkmcnt(0)" ::: "memory");
        __builtin_amdgcn_s_barrier();
    }
}

// ---------------------------------------------------------------------------
// MFMA GEMM (unchanged): global_load_lds staging, XOR-swizzled via
// pre-swizzled global source, 4 waves (2x2).  MODE 0: per-head, bf16+bias.
// MODE 1: bf16, gelu(+bias).  MODE 2: f32, +bias +residual(bf16).
// ---------------------------------------------------------------------------
template <int BM, int BN, int MODE>
__global__ __launch_bounds__(256) void gemm_mf(
    const unsigned short* __restrict__ A, int lda,
    const unsigned short* __restrict__ BT,
    const float* __restrict__ bias,
    void* __restrict__ Cout, int ldc,
    const unsigned short* __restrict__ res, int K) {
    __shared__ unsigned short Al[BM * 64];
    __shared__ unsigned short Bl[BN * 64];
    int m0 = blockIdx.x * BM;
    int n0;
    const unsigned short* Ap = A;
    const unsigned short* Bp;
    const float* bp;
    if (MODE == 0) {
        int h = blockIdx.y;
        Ap = A + (size_t)h * 512;
        Bp = BT + (size_t)h * 64 * K;
        bp = bias + h * 64;
        n0 = h * 64;
    } else {
        n0 = blockIdx.y * BN;
        Bp = BT + (size_t)n0 * K;
        bp = bias + n0;
    }
    int tid = threadIdx.x, l = tid & 63, w = tid >> 6;
    int lr = l & 15, lq = l >> 4;
    int wm = w >> 1, wn = w & 1;
    constexpr int MR = BM / 32, NR = BN / 32;
    constexpr int AI = BM / 8, BI = BN / 8;

    f32x4 acc[MR][NR];
    #pragma unroll
    for (int mi = 0; mi < MR; ++mi)
        #pragma unroll
        for (int nj = 0; nj < NR; ++nj) acc[mi][nj] = (f32x4){0.f, 0.f, 0.f, 0.f};

    int srow = l >> 3;
    int scol = ((l & 7) ^ ((l >> 3) & 7)) << 3;

    for (int k0 = 0; k0 < K; k0 += 64) {
        #pragma unroll
        for (int j = 0; j < AI / 4; ++j) {
            int ji = w * (AI / 4) + j;
            const unsigned short* src = Ap + (size_t)(m0 + ji * 8 + srow) * lda + k0 + scol;
            gload_lds16(src, &Al[ji * 512]);
        }
        #pragma unroll
        for (int j = 0; j < BI / 4; ++j) {
            int ji = w * (BI / 4) + j;
            const unsigned short* src = Bp + (size_t)(ji * 8 + srow) * K + k0 + scol;
            gload_lds16(src, &Bl[ji * 512]);
        }
        __syncthreads();
        #pragma unroll
        for (int kk = 0; kk < 64; kk += 32) {
            int sw = (kk + lq * 8) ^ ((l & 7) << 3);
            short8 af[MR], bf[NR];
            #pragma unroll
            for (int mi = 0; mi < MR; ++mi)
                af[mi] = *(const short8*)&Al[(wm * (BM / 2) + mi * 16 + lr) * 64 + sw];
            #pragma unroll
            for (int nj = 0; nj < NR; ++nj)
                bf[nj] = *(const short8*)&Bl[(wn * (BN / 2) + nj * 16 + lr) * 64 + sw];
            #pragma unroll
            for (int mi = 0; mi < MR; ++mi)
                #pragma unroll
                for (int nj = 0; nj < NR; ++nj)
                    acc[mi][nj] = __builtin_amdgcn_mfma_f32_16x16x32_bf16(
                        af[mi], bf[nj], acc[mi][nj], 0, 0, 0);
        }
        __syncthreads();
    }

    #pragma unroll
    for (int mi = 0; mi < MR; ++mi) {
        #pragma unroll
        for (int nj = 0; nj < NR; ++nj) {
            #pragma unroll
            for (int j = 0; j < 4; ++j) {
                int row = m0 + wm * (BM / 2) + mi * 16 + lq * 4 + j;
                int nl = wn * (BN / 2) + nj * 16 + lr;
                int col = n0 + nl;
                float v = acc[mi][nj][j] + bp[nl];
                if (MODE == 1) {
                    v = 0.5f * v * (1.0f + erff(v * 0.70710678118654752f));
                }
                if (MODE == 2) {
                    v += bf2f(res[(size_t)row * 512 + col]);
                    ((float*)Cout)[(size_t)row * ldc + col] = v;
                } else {
                    ((unsigned short*)Cout)[(size_t)row * ldc + col] = f2bf(v);
                }
            }
        }
    }
}

// ---------------------------------------------------------------------------
// K5: in-place LayerNorm over 512, one wave per row
// ---------------------------------------------------------------------------
__global__ __launch_bounds__(256) void ln_kernel(
    float* __restrict__ y, const float* __restrict__ g, const float* __restrict__ bta) {
    int row = blockIdx.x * 4 + (threadIdx.x >> 6);
    int l = threadIdx.x & 63;
    float* yp = y + (size_t)row * D_MODEL;
    float4 v0 = *(const float4*)(yp + l * 8);
    float4 v1 = *(const float4*)(yp + l * 8 + 4);
    float vv[8] = {v0.x, v0.y, v0.z, v0.w, v1.x, v1.y, v1.z, v1.w};
    float s = 0.f;
    #pragma unroll
    for (int i = 0; i < 8; ++i) s += vv[i];
    s = wave_sum(s);
    float mean = s * (1.f / 512.f);
    float q = 0.f;
    #pragma unroll
    for (int i = 0; i < 8; ++i) { float d = vv[i] - mean; q += d * d; }
    q = wave_sum(q);
    float rstd = rsqrtf(q * (1.f / 512.f) + 1e-5f);
    float4 g0 = *(const float4*)(g + l * 8);
    float4 g1 = *(const float4*)(g + l * 8 + 4);
    float4 b0 = *(const float4*)(bta + l * 8);
    float4 b1 = *(const float4*)(bta + l * 8 + 4);
    float gv[8] = {g0.x, g0.y, g0.z, g0.w, g1.x, g1.y, g1.z, g1.w};
    float bv[8] = {b0.x, b0.y, b0.z, b0.w, b1.x, b1.y, b1.z, b1.w};
    float ov[8];
    #pragma unroll
    for (int i = 0; i < 8; ++i) ov[i] = (vv[i] - mean) * rstd * gv[i] + bv[i];
    float4 o0 = {ov[0], ov[1], ov[2], ov[3]};
    float4 o1 = {ov[4], ov[5], ov[6], ov[7]};
    *(float4*)(yp + l * 8) = o0;
    *(float4*)(yp + l * 8 + 4) = o1;
}

extern "C" void kernel_launch(void* const* d_in, const int* in_sizes, int n_in,
                              void* d_out, int out_size, void* d_ws, size_t ws_size,
                              hipStream_t stream) {
    const float* x       = (const float*)d_in[0];
    const float* Wk      = (const float*)d_in[1];
    const float* Wv      = (const float*)d_in[3];
    const float* bv      = (const float*)d_in[4];
    const float* score_w = (const float*)d_in[5];
    const float* W1      = (const float*)d_in[7];
    const float* b1      = (const float*)d_in[8];
    const float* W2      = (const float*)d_in[9];
    const float* b2      = (const float*)d_in[10];
    const float* ln_g    = (const float*)d_in[11];
    const float* ln_b    = (const float*)d_in[12];
    float* out = (float*)d_out;

    char* ws = (char*)d_ws;
    size_t off = 0;
    auto alloc = [&](size_t sz) {
        void* p = ws + off;
        off = (off + sz + 1023) & ~(size_t)1023;
        return p;
    };
    unsigned short* uT  = (unsigned short*)alloc((size_t)16 * D_MODEL * 2);
    unsigned short* WvT = (unsigned short*)alloc((size_t)512 * 512 * 2);
    unsigned short* W1T = (unsigned short*)alloc((size_t)2048 * 512 * 2);
    unsigned short* W2T = (unsigned short*)alloc((size_t)512 * 2048 * 2);
    unsigned short* pooled = (unsigned short*)alloc((size_t)BATCH * N_HEAD * D_MODEL * 2);
    unsigned short* feat   = (unsigned short*)alloc((size_t)BATCH * D_MODEL * 2);
    unsigned short* Hbuf   = (unsigned short*)alloc((size_t)BATCH * D_HIDDEN * 2);

    prep_all<<<dim3(1024, 4), dim3(256), 0, stream>>>(
        Wk, score_w, Wv, W1, W2, uT, WvT, W1T, W2T);
    score_pool_v5<<<dim3(512), dim3(512), 0, stream>>>(x, uT, pooled);
    // proj: feature = pooled @ blockdiag(Wv per head) + bv
    gemm_mf<128, 64, 0><<<dim3(32, 8), dim3(256), 0, stream>>>(
        pooled, N_HEAD * D_MODEL, WvT, bv, (void*)feat, D_MODEL,
        (const unsigned short*)nullptr, 512);
    // ffn1: H = gelu(feature @ W1 + b1)
    gemm_mf<128, 128, 1><<<dim3(32, 16), dim3(256), 0, stream>>>(
        feat, D_MODEL, W1T, b1, (void*)Hbuf, D_HIDDEN,
        (const unsigned short*)nullptr, 512);
    // ffn2: y = H @ W2 + b2 + feature  (f32 -> d_out)
    gemm_mf<64, 128, 2><<<dim3(64, 4), dim3(256), 0, stream>>>(
        Hbuf, D_HIDDEN, W2T, b2, (void*)out, D_MODEL, feat, 2048);
    ln_kernel<<<dim3(1024), dim3(256), 0, stream>>>(out, ln_g, ln_b);
}